// Round 1
// baseline (1215.754 us; speedup 1.0000x reference)
//
#include <hip/hip_runtime.h>

#define NT 128
#define SS 512

typedef float f32x2 __attribute__((ext_vector_type(2)));
typedef float f32x4 __attribute__((ext_vector_type(4)));

__device__ __forceinline__ int fexp_of(float x) {
    return (int)((__float_as_uint(x) >> 23) & 0xFFu) - 127;
}

__global__ void zero_out_kernel(float* out) { out[0] = 0.0f; }

// Single-wave-per-batch forward recursion: no barriers, no cross-wave exchange.
// Lane l owns states {l, l+64}; exp(T) columns for those states live in 256 VGPRs.
// Alpha broadcast via duplicated LDS layout: abuf4[j] = {a[2j],a[2j],a[2j+1],a[2j+1]}
// so one uniform-address ds_read_b128 feeds two v_pk_fma_f32 with zero packing movs.
__global__ __launch_bounds__(64, 1) void crf_fwd_kernel(
    const float* __restrict__ emissions,        // [B, S, NT] f32
    const int* __restrict__ tags,               // [B, S]
    const unsigned char* __restrict__ mask,     // [B, S]
    const float* __restrict__ trans,            // [NT, NT] f32
    float* __restrict__ out)                    // [1] f32
{
    const int b = blockIdx.x;                   // one batch per block (256 blocks)
    const int l = threadIdx.x;                  // 0..63, single wave

    __shared__ f32x4 abuf4[NT / 2];             // 1 KiB: dup alpha pairs
    float* abufF = (float*)abuf4;

    const float*         emB = emissions + (size_t)b * SS * NT;
    const int*           tgB = tags + b * SS;
    const unsigned char* mkB = mask + b * SS;

    // ---- gold score (one-time, off the recursion) ----
    float gold = 0.0f;
    #pragma unroll
    for (int k = 0; k < SS / 64; k++) {
        int t    = l + 64 * k;
        int tg   = tgB[t];
        float mk = mkB[t] ? 1.0f : 0.0f;
        float a  = emB[(size_t)t * NT + tg];
        if (t > 0) a += trans[tgB[t - 1] * NT + tg];
        gold += a * mk;
    }

    // ---- exp(T): all 128 rows for own 2 columns -> 256 VGPRs ----
    f32x2 eTr[NT];
    #pragma unroll
    for (int r = 0; r < NT; r++) {
        const float* row = trans + (size_t)r * NT;
        f32x2 v; v.x = __expf(row[l]); v.y = __expf(row[l + 64]);
        eTr[r] = v;
    }

    // ---- init: p = exp(a0 - M0), M0 = max over states ----
    f32x2 a0; a0.x = emB[l]; a0.y = emB[l + 64];
    float m = fmaxf(a0.x, a0.y);
    #pragma unroll
    for (int o = 32; o > 0; o >>= 1) m = fmaxf(m, __shfl_xor(m, o));
    const float M0 = m;

    f32x2 p; p.x = __expf(a0.x - M0); p.y = __expf(a0.y - M0);
    float S = 0.0f;
    int K = 0, kv_red = 0;

    // ---- emission pipeline: loads 4 deep, exp 2 steps off-chain ----
    f32x2 ex_o, ex_e, pd_o, pd_e;
    ex_o.x = __expf(emB[(size_t)1 * NT + l]); ex_o.y = __expf(emB[(size_t)1 * NT + l + 64]);
    ex_e.x = __expf(emB[(size_t)2 * NT + l]); ex_e.y = __expf(emB[(size_t)2 * NT + l + 64]);
    pd_o.x = emB[(size_t)3 * NT + l];         pd_o.y = emB[(size_t)3 * NT + l + 64];
    pd_e.x = emB[(size_t)4 * NT + l];         pd_e.y = emB[(size_t)4 * NT + l + 64];

    // publish p (duplicated), then accumulate all 128 rows; same-wave DS order
    // makes the write->read hazard sync-free.
    auto matvec = [&]() -> f32x2 {
        f32x2 d0; d0.x = p.x; d0.y = p.x;
        f32x2 d1; d1.x = p.y; d1.y = p.y;
        *(f32x2*)&abufF[2 * l]        = d0;     // ds_write_b64 @ 8l
        *(f32x2*)&abufF[2 * (l + 64)] = d1;     // ds_write_b64 @ 8l+512
        f32x2 A0 = {0.f, 0.f}, A1 = {0.f, 0.f}, A2 = {0.f, 0.f}, A3 = {0.f, 0.f};
        #pragma unroll
        for (int j = 0; j < NT / 2; j += 2) {
            f32x4 v0 = abuf4[j];                // {a,a,a',a'} rows 2j, 2j+1
            f32x4 v1 = abuf4[j + 1];            // rows 2j+2, 2j+3
            f32x2 b00; b00.x = v0.x; b00.y = v0.y;
            f32x2 b01; b01.x = v0.z; b01.y = v0.w;
            f32x2 b10; b10.x = v1.x; b10.y = v1.y;
            f32x2 b11; b11.x = v1.z; b11.y = v1.w;
            A0 = __builtin_elementwise_fma(b00, eTr[2 * j + 0], A0);
            A1 = __builtin_elementwise_fma(b01, eTr[2 * j + 1], A1);
            A2 = __builtin_elementwise_fma(b10, eTr[2 * j + 2], A2);
            A3 = __builtin_elementwise_fma(b11, eTr[2 * j + 3], A3);
        }
        return (A0 + A1) + (A2 + A3);
    };
    auto rot = [&](int t, f32x2& pd, f32x2& ex) {
        f32x2 nr = pd;
        int tn = t + 4; if (tn > SS - 1) tn = SS - 1;
        pd.x = emB[(size_t)tn * NT + l];
        pd.y = emB[(size_t)tn * NT + l + 64];
        ex.x = __expf(nr.x);
        ex.y = __expf(nr.y);
    };

    // ---- forward recursion: groups of 4 steps; rescale at sub-step 0 ----
    #pragma unroll 1
    for (int t = 1; t < SS; t += 4) {
        {   // sub 0: apply K, propose next kv (in-wave shuffle reduce, hidden)
            f32x2 exu = ex_o; rot(t, pd_o, ex_o);       // free compiler to hoist
            f32x2 sn = matvec();
            sn.x *= exu.x; sn.y *= exu.y;
            p.x = ldexpf(sn.x, -K); p.y = ldexpf(sn.y, -K);
            S += (float)K;
            int kv = max(fexp_of(p.x), fexp_of(p.y));
            #pragma unroll
            for (int o = 32; o > 0; o >>= 1) kv = max(kv, __shfl_xor(kv, o));
            kv_red = kv;
        }
        if (t + 1 < SS) {
            f32x2 exu = ex_e; rot(t + 1, pd_e, ex_e);
            f32x2 sn = matvec();
            p.x = sn.x * exu.x; p.y = sn.y * exu.y;
        }
        if (t + 2 < SS) {
            f32x2 exu = ex_o; rot(t + 2, pd_o, ex_o);
            f32x2 sn = matvec();
            p.x = sn.x * exu.x; p.y = sn.y * exu.y;
            K = kv_red;                                 // slack: applied next sub0
        }
        if (t + 3 < SS) {
            f32x2 exu = ex_e; rot(t + 3, pd_e, ex_e);
            f32x2 sn = matvec();
            p.x = sn.x * exu.x; p.y = sn.y * exu.y;
        }
    }

    // ---- epilogue: partition = M0 + S*ln2 + log Σ p̂ ; reduce gold ----
    float tot = p.x + p.y;
    float g   = gold;
    #pragma unroll
    for (int o = 32; o > 0; o >>= 1) {
        tot += __shfl_xor(tot, o);
        g   += __shfl_xor(g, o);
    }
    if (l == 0) {
        float part = M0 + S * 0.69314718055994531f + __logf(tot);
        atomicAdd(out, part - g);
    }
}

extern "C" void kernel_launch(void* const* d_in, const int* in_sizes, int n_in,
                              void* d_out, int out_size, void* d_ws, size_t ws_size,
                              hipStream_t stream) {
    const float*         emissions = (const float*)d_in[0];
    const int*           tags      = (const int*)d_in[1];
    const unsigned char* mask      = (const unsigned char*)d_in[2];
    const float*         trans     = (const float*)d_in[3];
    float*               out       = (float*)d_out;

    zero_out_kernel<<<1, 1, 0, stream>>>(out);
    crf_fwd_kernel<<<256, 64, 0, stream>>>(emissions, tags, mask, trans, out);
}

// Round 2
// 253.464 us; speedup vs baseline: 4.7966x; 4.7966x over previous
//
#include <hip/hip_runtime.h>

#define NT 128
#define SS 512
#define NW 8                            // waves per block
#define RW 16                           // rows per wave
#define PW 132                          // padded per-wave column stride (floats)

typedef float f32x2 __attribute__((ext_vector_type(2)));

__device__ __forceinline__ float rdlane(float v, int lane) {
    return __int_as_float(__builtin_amdgcn_readlane(__float_as_int(v), lane));
}
__device__ __forceinline__ int fexp_of(float x) {
    return (int)((__float_as_uint(x) >> 23) & 0xFFu) - 127;
}
// barrier draining only LDS ops — global prefetches stay in flight
__device__ __forceinline__ void lds_barrier() {
    asm volatile("s_waitcnt lgkmcnt(0)\n\ts_barrier" ::: "memory");
}

__global__ void zero_out_kernel(float* out) { out[0] = 0.0f; }

// 8 waves x 16 rows: finer matvec split cuts per-wave issue ~2.7x so the
// per-step serial chain (barrier + LDS RT + combine) becomes the floor.
__global__ __launch_bounds__(512, 1) void crf_fwd_kernel(
    const float* __restrict__ emissions,        // [B, S, NT] f32
    const int* __restrict__ tags,               // [B, S]
    const unsigned char* __restrict__ mask,     // [B, S]
    const float* __restrict__ trans,            // [NT, NT] f32
    float* __restrict__ out)                    // [1] f32
{
    const int b   = blockIdx.x;                 // one batch per block
    const int tid = threadIdx.x;                // 0..511
    const int l   = tid & 63;
    const int w   = tid >> 6;                   // wave 0..7: rows 16w..16w+15
    const int st  = (w << 4) + (l & 15);        // owned state (dup x4 on lanes)

    __shared__ float pbuf[2][NW * PW];          // [parity][wave*PW + col]
    __shared__ int   kbuf[NW];
    __shared__ float redf[NW];
    __shared__ float redg[NW];

    const float*         emB = emissions + (size_t)b * SS * NT;
    const int*           tgB = tags + b * SS;
    const unsigned char* mkB = mask + b * SS;

    // ---- gold score fully hoisted off the recursion (1 elem/thread) ----
    float gold;
    {
        int t    = tid;                         // SS == 512 == blockDim
        int tg   = tgB[t];
        float mk = mkB[t] ? 1.0f : 0.0f;
        float a  = emB[(size_t)t * NT + tg];
        if (t > 0) a += trans[tgB[t - 1] * NT + tg];
        gold = a * mk;
    }

    // ---- expT: own 16 rows, cols {l, l+64} packed -> 32 VGPRs ----
    f32x2 eTr[RW];
    #pragma unroll
    for (int r = 0; r < RW; r++) {
        const float* row = trans + (size_t)((w << 4) + r) * NT;
        f32x2 v; v.x = __expf(row[l]); v.y = __expf(row[l + 64]);
        eTr[r] = v;
    }

    // ---- init: true alpha_j = p̂ * 2^S * e^{M0} (S global) ----
    float a0 = emB[st];
    {
        float v = a0;
        #pragma unroll
        for (int o = 16; o > 0; o >>= 1) v = fmaxf(v, __shfl_xor(v, o));
        if (l == 0) redf[w] = v;
    }
    __syncthreads();
    float M0 = redf[0];
    #pragma unroll
    for (int i = 1; i < NW; i++) M0 = fmaxf(M0, redf[i]);

    float p = __expf(a0 - M0);                  // p̂ for state st (dup x4)
    float S = 0.0f;
    int K = 0, kv_own = 0;

    // ---- emission pipeline: loads 4 deep, exp 2 steps off-chain ----
    float ex_o = __expf(emB[(size_t)1 * NT + st]);
    float ex_e = __expf(emB[(size_t)2 * NT + st]);
    float pd_o = emB[(size_t)3 * NT + st];
    float pd_e = emB[(size_t)4 * NT + st];

    // matvec over own 16 rows + 8-way partial combine; 1 lgkm barrier
    auto matvec = [&](int q, bool kw) -> float {
        f32x2 A0 = {0.f,0.f}, A1 = {0.f,0.f}, A2 = {0.f,0.f}, A3 = {0.f,0.f};
        #pragma unroll
        for (int r = 0; r < RW; r += 4) {
            float q0 = rdlane(p, r + 0);
            float q1 = rdlane(p, r + 1);
            float q2 = rdlane(p, r + 2);
            float q3 = rdlane(p, r + 3);
            f32x2 b0 = {q0, q0}, b1 = {q1, q1}, b2 = {q2, q2}, b3 = {q3, q3};
            A0 = __builtin_elementwise_fma(b0, eTr[r + 0], A0);
            A1 = __builtin_elementwise_fma(b1, eTr[r + 1], A1);
            A2 = __builtin_elementwise_fma(b2, eTr[r + 2], A2);
            A3 = __builtin_elementwise_fma(b3, eTr[r + 3], A3);
        }
        f32x2 s2 = (A0 + A1) + (A2 + A3);       // {partial col l, partial col l+64}
        pbuf[q][w * PW + l]      = s2.x;
        pbuf[q][w * PW + l + 64] = s2.y;
        if (kw && l == 0) kbuf[w] = kv_own;     // rides the barrier
        lds_barrier();                          // lgkm-only: vmcnt untouched
        float c0 = pbuf[q][0 * PW + st], c1 = pbuf[q][1 * PW + st];
        float c2 = pbuf[q][2 * PW + st], c3 = pbuf[q][3 * PW + st];
        float c4 = pbuf[q][4 * PW + st], c5 = pbuf[q][5 * PW + st];
        float c6 = pbuf[q][6 * PW + st], c7 = pbuf[q][7 * PW + st];
        return ((c0 + c1) + (c2 + c3)) + ((c4 + c5) + (c6 + c7));
    };
    auto rot = [&](int t, float& pd, float& ex) {
        float nr = pd;
        int tn = t + 4; if (tn > SS - 1) tn = SS - 1;
        pd = emB[(size_t)tn * NT + st];
        ex = __expf(nr);
    };

    // ---- forward recursion: groups of 4 steps; rescale at sub-step 0 ----
    #pragma unroll 1
    for (int t = 1; t < SS; t += 4) {
        {   // sub 0 (parity 1): apply K, propose next kv
            float sn = matvec(1, false) * ex_o;
            p = ldexpf(sn, -K);
            S += (float)K;
            int kv = fexp_of(p);
            #pragma unroll
            for (int o = 16; o > 0; o >>= 1) kv = max(kv, __shfl_xor(kv, o));
            kv_own = kv;
            rot(t, pd_o, ex_o);
        }
        if (t + 1 < SS) {   // sub 1 (parity 0): K exchange piggyback
            float sn = matvec(0, true) * ex_e;
            int k0 = max(kbuf[0], kbuf[1]), k1 = max(kbuf[2], kbuf[3]);
            int k2 = max(kbuf[4], kbuf[5]), k3 = max(kbuf[6], kbuf[7]);
            K = max(max(k0, k1), max(k2, k3));
            p = sn;
            rot(t + 1, pd_e, ex_e);
        }
        if (t + 2 < SS) { p = matvec(1, false) * ex_o; rot(t + 2, pd_o, ex_o); }
        if (t + 3 < SS) { p = matvec(0, false) * ex_e; rot(t + 3, pd_e, ex_e); }
    }

    // ---- epilogue: partition = M0 + S*ln2 + log Σ p̂ ; reduce gold ----
    {
        float sw = (l < 16) ? p : 0.0f;         // states dup x4 across lanes
        float g  = gold;
        #pragma unroll
        for (int o = 32; o > 0; o >>= 1) {
            sw += __shfl_xor(sw, o);
            g  += __shfl_xor(g, o);
        }
        if (l == 0) { redf[w] = sw; redg[w] = g; }
    }
    __syncthreads();
    if (tid == 0) {
        float tot = 0.0f, gt = 0.0f;
        #pragma unroll
        for (int i = 0; i < NW; i++) { tot += redf[i]; gt += redg[i]; }
        float part = M0 + S * 0.69314718055994531f + __logf(tot);
        atomicAdd(out, part - gt);
    }
}

extern "C" void kernel_launch(void* const* d_in, const int* in_sizes, int n_in,
                              void* d_out, int out_size, void* d_ws, size_t ws_size,
                              hipStream_t stream) {
    const float*         emissions = (const float*)d_in[0];
    const int*           tags      = (const int*)d_in[1];
    const unsigned char* mask      = (const unsigned char*)d_in[2];
    const float*         trans     = (const float*)d_in[3];
    float*               out       = (float*)d_out;

    zero_out_kernel<<<1, 1, 0, stream>>>(out);
    crf_fwd_kernel<<<256, 512, 0, stream>>>(emissions, tags, mask, trans, out);
}